// Round 5
// baseline (428.347 us; speedup 1.0000x reference)
//
#include <hip/hip_runtime.h>
#include <math.h>

#define NN    8
#define CC    256
#define HWHW  16384
#define NBOX  20
#define HALF  131072   // NN*HWHW: stride between cs-halves of per-pixel arrays

constexpr float C_ALPHA = 1e-3f, C_BETA = 5e-4f, C_GAMMA = 1e-3f, C_LAMB = 5e-6f;
constexpr float C_LN_EPS = 1e-5f;

// ws layout (float offsets)
#define OFF_FEA_S   0          // [2][N][HW] per-cs-half partial |x| channel-sums
#define OFF_FEA_T   262144
#define OFF_CM_S    524288     // [2][N][HW] per-cs-half partial spatial-pool logits
#define OFF_CM_T    786432
#define OFF_MFG     1048576    // [N][HW]
// --- zeroed-by-k0 region: 10256 floats from OFF_CHS ---
#define OFF_CHS     1179648    // [N][C] sum |S| over pixels (k1 atomics)
#define OFF_CHT     1181696    // [N][C]
#define OFF_DSUM    1183744    // [N][C] sum (S-T) (k1 atomics)
#define OFF_CTXS    1185792    // [N][C] (k4 atomics)
#define OFF_CTXT    1187840    // [N][C]
#define OFF_BG      1189888    // [8] (written by k2C; zeroing harmless)
#define OFF_SCAL    1189896    // [8] 0: sum(S-T)^2, 1: fg/bg, 2: macc, 3: ticket
// --- end zero region ---
#define OFF_CATT    1189904    // [N][C]
#define OFF_STATS   1191952    // [N*8] {mxFS,ZFS,mxFT,ZFT,mxCS,ZCS,mxCT,ZCT}
#define OFF_RELAP   1193040    // [8]
#define OFF_BGP     1193048    // [8][16] per-(n,pbB) bg-count partials
#define OFF_MML     1193176    // [8] per-n channel-mask-loss
#define ZERO_SPAN   10256

// ---- wave-64 reductions via DPP ----
__device__ __forceinline__ float dpp_wave_sum(float x) {
#define DPPADD(ctrl, rm) \
  x += __int_as_float(__builtin_amdgcn_update_dpp(0, __float_as_int(x), ctrl, rm, 0xf, true));
  DPPADD(0x111, 0xf)
  DPPADD(0x112, 0xf)
  DPPADD(0x114, 0xf)
  DPPADD(0x118, 0xf)
  DPPADD(0x142, 0xa)
  DPPADD(0x143, 0xc)
#undef DPPADD
  return x;  // total in lane 63
}

__device__ __forceinline__ float dpp_wave_max(float x) {
#define DPPMAX(ctrl, rm) { \
  int r_ = __builtin_amdgcn_update_dpp(__float_as_int(x), __float_as_int(x), ctrl, rm, 0xf, false); \
  x = fmaxf(x, __int_as_float(r_)); }
  DPPMAX(0x111, 0xf)
  DPPMAX(0x112, 0xf)
  DPPMAX(0x114, 0xf)
  DPPMAX(0x118, 0xf)
  DPPMAX(0x142, 0xa)
  DPPMAX(0x143, 0xc)
#undef DPPMAX
  return x;
}

__device__ __forceinline__ float block_sum256(float v, float* sm) {
  int tid = threadIdx.x;
  v = dpp_wave_sum(v);
  if ((tid & 63) == 63) sm[tid >> 6] = v;
  __syncthreads();
  float r = sm[0] + sm[1] + sm[2] + sm[3];
  __syncthreads();
  return r;
}

__device__ __forceinline__ float block_max256(float v, float* sm) {
  int tid = threadIdx.x;
  v = dpp_wave_max(v);
  if ((tid & 63) == 63) sm[tid >> 6] = v;
  __syncthreads();
  float r = fmaxf(fmaxf(sm[0], sm[1]), fmaxf(sm[2], sm[3]));
  __syncthreads();
  return r;
}

// ---- K0: mask rasterization + zero the atomic-accumulator region.
// grid (16 pbB, 8 n) x 256. Replaces the hipMemsetAsync dispatch + k2B phase A.
__global__ __launch_bounds__(256) void k0_maskzero(const float* __restrict__ gt,
                                                   float* __restrict__ ws) {
  int tid = threadIdx.x;
  int pbB = blockIdx.x, n = blockIdx.y;
  int pix0 = pbB * 1024 + tid * 4;

  // zero the accumulator span (CHS..SCAL incl. ticket at SCAL[3])
  int gi = (n * 16 + pbB) * 256 + tid;
  if (gi < ZERO_SPAN) ws[OFF_CHS + gi] = 0.f;

  __shared__ float bx[NBOX][5];
  __shared__ float l_bg[4];

  if (tid < NBOX) {
    const float* g = gt + (n * NBOX + tid) * 4;
    float wmin = floorf(g[0] * 0.125f);
    float hmin = floorf(g[1] * 0.125f);
    float wmax = ceilf(g[2] * 0.125f);
    float hmax = ceilf(g[3] * 0.125f);
    bx[tid][0] = wmin; bx[tid][1] = hmin; bx[tid][2] = wmax; bx[tid][3] = hmax;
    bx[tid][4] = 1.0f / ((hmax + 1.0f - hmin) * (wmax + 1.0f - wmin));
  }
  __syncthreads();

  float best[4] = {0.f, 0.f, 0.f, 0.f};
#pragma unroll
  for (int b = 0; b < NBOX; b++) {
    float wmin = bx[b][0], hmin = bx[b][1], wmax = bx[b][2], hmax = bx[b][3];
    float ar = bx[b][4];
#pragma unroll
    for (int j = 0; j < 4; j++) {
      int pix = pix0 + j;
      float hf = (float)(pix >> 7), wf = (float)(pix & 127);
      bool in = (hf >= hmin) && (hf <= hmax) && (wf >= wmin) && (wf <= wmax);
      best[j] = in ? fmaxf(best[j], ar) : best[j];
    }
  }
  float4 bo;
  bo.x = best[0]; bo.y = best[1]; bo.z = best[2]; bo.w = best[3];
  *(float4*)&ws[OFF_MFG + n * HWHW + pix0] = bo;

  float bg = (best[0] > 0.f ? 0.f : 1.f) + (best[1] > 0.f ? 0.f : 1.f) +
             (best[2] > 0.f ? 0.f : 1.f) + (best[3] > 0.f ? 0.f : 1.f);
  bg = dpp_wave_sum(bg);
  if ((tid & 63) == 63) l_bg[tid >> 6] = bg;
  __syncthreads();
  if (tid == 0)
    ws[OFF_BGP + n * 16 + pbB] = l_bg[0] + l_bg[1] + l_bg[2] + l_bg[3];
}

// ---- K1: pass 1. grid (64 pb, 2 cs, 8 n) x 512 thr. (measured-best R2 body)
__global__ __launch_bounds__(512, 2) void k1_pass1(
    const float* __restrict__ S, const float* __restrict__ T,
    const float* __restrict__ w_ms, const float* __restrict__ w_mt,
    float* __restrict__ ws) {
  int tid = threadIdx.x;
  int lane = tid & 63, sl = tid >> 6;
  int pb = blockIdx.x, cs = blockIdx.y, n = blockIdx.z;
  int pix0 = pb * 256 + lane * 4;
  int ch0 = cs * 128 + sl * 16;

  __shared__ float l_wS[128], l_wT[128];
  __shared__ float f_feaS[256], f_feaT[256], f_cmS[256], f_cmT[256];
  __shared__ float l_chS[128], l_chT[128], l_D[128];
  __shared__ float l_sq[8];

  if (tid < 128) {
    l_wS[tid] = w_ms[cs * 128 + tid];
    l_wT[tid] = w_mt[cs * 128 + tid];
  }
  if (tid < 256) {
    f_feaS[tid] = 0.f; f_feaT[tid] = 0.f; f_cmS[tid] = 0.f; f_cmT[tid] = 0.f;
  }
  __syncthreads();

  const float* baseS = S + (size_t)(n * CC + ch0) * HWHW + pix0;
  const float* baseT = T + (size_t)(n * CC + ch0) * HWHW + pix0;

  float fS[4] = {0.f, 0.f, 0.f, 0.f}, fT[4] = {0.f, 0.f, 0.f, 0.f};
  float cS[4] = {0.f, 0.f, 0.f, 0.f}, cT[4] = {0.f, 0.f, 0.f, 0.f};
  float sq = 0.f;

#define PROC1(c, s4, t4, wS_, wT_) { \
    float asx = fabsf(s4.x), asy = fabsf(s4.y), asz = fabsf(s4.z), asw = fabsf(s4.w); \
    float atx = fabsf(t4.x), aty = fabsf(t4.y), atz = fabsf(t4.z), atw = fabsf(t4.w); \
    fS[0] += asx; fS[1] += asy; fS[2] += asz; fS[3] += asw; \
    fT[0] += atx; fT[1] += aty; fT[2] += atz; fT[3] += atw; \
    chS[c] = (asx + asy) + (asz + asw); \
    chT[c] = (atx + aty) + (atz + atw); \
    cS[0] = fmaf(s4.x, wS_, cS[0]); cS[1] = fmaf(s4.y, wS_, cS[1]); \
    cS[2] = fmaf(s4.z, wS_, cS[2]); cS[3] = fmaf(s4.w, wS_, cS[3]); \
    cT[0] = fmaf(t4.x, wT_, cT[0]); cT[1] = fmaf(t4.y, wT_, cT[1]); \
    cT[2] = fmaf(t4.z, wT_, cT[2]); cT[3] = fmaf(t4.w, wT_, cT[3]); \
    float dx = s4.x - t4.x, dy = s4.y - t4.y, dz = s4.z - t4.z, dw = s4.w - t4.w; \
    sq = fmaf(dx, dx, sq); sq = fmaf(dy, dy, sq); \
    sq = fmaf(dz, dz, sq); sq = fmaf(dw, dw, sq); \
    D[c] = (dx + dy) + (dz + dw); }

#pragma unroll 1
  for (int cg = 0; cg < 4; cg++) {
    const float* bS = baseS + (size_t)(cg * 4) * HWHW;
    const float* bT = baseT + (size_t)(cg * 4) * HWHW;
    float4 s0 = *(const float4*)(bS + (size_t)0 * HWHW);
    float4 s1 = *(const float4*)(bS + (size_t)1 * HWHW);
    float4 s2 = *(const float4*)(bS + (size_t)2 * HWHW);
    float4 s3 = *(const float4*)(bS + (size_t)3 * HWHW);
    float4 t0 = *(const float4*)(bT + (size_t)0 * HWHW);
    float4 t1 = *(const float4*)(bT + (size_t)1 * HWHW);
    float4 t2 = *(const float4*)(bT + (size_t)2 * HWHW);
    float4 t3 = *(const float4*)(bT + (size_t)3 * HWHW);
    float wS0 = l_wS[sl * 16 + cg * 4 + 0], wT0 = l_wT[sl * 16 + cg * 4 + 0];
    float wS1 = l_wS[sl * 16 + cg * 4 + 1], wT1 = l_wT[sl * 16 + cg * 4 + 1];
    float wS2 = l_wS[sl * 16 + cg * 4 + 2], wT2 = l_wT[sl * 16 + cg * 4 + 2];
    float wS3 = l_wS[sl * 16 + cg * 4 + 3], wT3 = l_wT[sl * 16 + cg * 4 + 3];
    float chS[4], chT[4], D[4];
    PROC1(0, s0, t0, wS0, wT0)
    PROC1(1, s1, t1, wS1, wT1)
    PROC1(2, s2, t2, wS2, wT2)
    PROC1(3, s3, t3, wS3, wT3)
#pragma unroll
    for (int c = 0; c < 4; c++) {
      float a = dpp_wave_sum(chS[c]);
      float b = dpp_wave_sum(chT[c]);
      float d = dpp_wave_sum(D[c]);
      if (lane == 63) {
        l_chS[sl * 16 + cg * 4 + c] = a;
        l_chT[sl * 16 + cg * 4 + c] = b;
        l_D[sl * 16 + cg * 4 + c]   = d;
      }
    }
  }
#undef PROC1

  atomicAdd(&f_feaS[lane * 4 + 0], fS[0]); atomicAdd(&f_feaS[lane * 4 + 1], fS[1]);
  atomicAdd(&f_feaS[lane * 4 + 2], fS[2]); atomicAdd(&f_feaS[lane * 4 + 3], fS[3]);
  atomicAdd(&f_feaT[lane * 4 + 0], fT[0]); atomicAdd(&f_feaT[lane * 4 + 1], fT[1]);
  atomicAdd(&f_feaT[lane * 4 + 2], fT[2]); atomicAdd(&f_feaT[lane * 4 + 3], fT[3]);
  atomicAdd(&f_cmS[lane * 4 + 0], cS[0]); atomicAdd(&f_cmS[lane * 4 + 1], cS[1]);
  atomicAdd(&f_cmS[lane * 4 + 2], cS[2]); atomicAdd(&f_cmS[lane * 4 + 3], cS[3]);
  atomicAdd(&f_cmT[lane * 4 + 0], cT[0]); atomicAdd(&f_cmT[lane * 4 + 1], cT[1]);
  atomicAdd(&f_cmT[lane * 4 + 2], cT[2]); atomicAdd(&f_cmT[lane * 4 + 3], cT[3]);

  sq = dpp_wave_sum(sq);
  if (lane == 63) l_sq[sl] = sq;
  __syncthreads();

  if (tid < 256) {
    int gp = cs * HALF + n * HWHW + pb * 256 + tid;
    ws[OFF_FEA_S + gp] = f_feaS[tid];
    ws[OFF_FEA_T + gp] = f_feaT[tid];
    ws[OFF_CM_S + gp]  = f_cmS[tid];
    ws[OFF_CM_T + gp]  = f_cmT[tid];
  }
  if (tid < 128) {
    int co = n * CC + cs * 128 + tid;
    atomicAdd(&ws[OFF_CHS + co],  l_chS[tid]);
    atomicAdd(&ws[OFF_CHT + co],  l_chT[tid]);
    atomicAdd(&ws[OFF_DSUM + co], l_D[tid]);
  }
  if (tid == 0) {
    float t = 0.f;
#pragma unroll
    for (int i = 0; i < 8; i++) t += l_sq[i];
    atomicAdd(&ws[OFF_SCAL + 0], t);
  }
}

// ---- K2C: all global stats in one kernel. grid 8 (n) x 256.
// BG sum + online softmax (m,Z) over the 4 per-pixel arrays + channel softmax.
__global__ __launch_bounds__(256) void k2C_stats(float* __restrict__ ws) {
  int tid = threadIdx.x, n = blockIdx.x;
  int lane = tid & 63;
  __shared__ float sm[4];
  __shared__ float wm[4], wz[4];

  if (tid == 0) {
    float b = 0.f;
    for (int i = 0; i < 16; i++) b += ws[OFF_BGP + n * 16 + i];
    ws[OFF_BG + n] = b;
  }

  const int   offs[4]   = {OFF_FEA_S, OFF_FEA_T, OFF_CM_S, OFF_CM_T};
  const float scales[4] = {1.0f / 128.0f, 1.0f / 128.0f, 1.0f, 1.0f};
#pragma unroll 1
  for (int a = 0; a < 4; a++) {
    float m = -1e30f, z = 0.f;
    int base = offs[a] + n * HWHW;
    float sc = scales[a];
    for (int k = 0; k < 16; k++) {
      int i = k * 1024 + tid * 4;
      float4 v0 = *(const float4*)&ws[base + i];
      float4 v1 = *(const float4*)&ws[base + HALF + i];
      float vv[4] = {(v0.x + v1.x) * sc, (v0.y + v1.y) * sc,
                     (v0.z + v1.z) * sc, (v0.w + v1.w) * sc};
#pragma unroll
      for (int j = 0; j < 4; j++) {
        float v = vv[j];
        float mn = fmaxf(m, v);
        z = z * expf(m - mn) + expf(v - mn);
        m = mn;
      }
    }
    // wave butterfly (m,z) combine
#pragma unroll
    for (int d = 1; d < 64; d <<= 1) {
      float m2 = __shfl_xor(m, d);
      float z2 = __shfl_xor(z, d);
      float mn = fmaxf(m, m2);
      z = z * expf(m - mn) + z2 * expf(m2 - mn);
      m = mn;
    }
    if (lane == 0) { wm[tid >> 6] = m; wz[tid >> 6] = z; }
    __syncthreads();
    if (tid == 0) {
      float M = wm[0], Z = wz[0];
      for (int w = 1; w < 4; w++) {
        float mn = fmaxf(M, wm[w]);
        Z = Z * expf(M - mn) + wz[w] * expf(wm[w] - mn);
        M = mn;
      }
      ws[OFF_STATS + n * 8 + 2 * a]     = M;
      ws[OFF_STATS + n * 8 + 2 * a + 1] = Z;
    }
    __syncthreads();
  }

  // channel softmax + CATT + per-n mask-loss part
  float chS = ws[OFF_CHS + n * CC + tid];
  float chT = ws[OFF_CHT + n * CC + tid];
  float lS = chS * (1.0f / 8192.0f), lT = chT * (1.0f / 8192.0f);
  float mS = block_max256(lS, sm);
  float mT = block_max256(lT, sm);
  float eS = expf(lS - mS), eT = expf(lT - mT);
  float ZS = block_sum256(eS, sm);
  float ZT = block_sum256(eT, sm);
  float cattS = (float)CC * eS / ZS;
  float cattT = (float)CC * eT / ZT;
  ws[OFF_CATT + n * CC + tid] = cattT;
  float mml = block_sum256(fabsf(cattS - cattT), sm);
  if (tid == 0) ws[OFF_MML + n] = mml;
}

// ---- K4: pass 2. grid (64 pb, 2 cs, 8 n) x 512 thr. (R4 body, unchanged)
__global__ __launch_bounds__(512, 2) void k4_pass2(
    const float* __restrict__ S, const float* __restrict__ T,
    float* __restrict__ ws) {
  int tid = threadIdx.x;
  int lane = tid & 63, sl = tid >> 6;
  int pb = blockIdx.x, cs = blockIdx.y, n = blockIdx.z;
  int pix0 = pb * 256 + lane * 4;
  int ch0 = cs * 128 + sl * 16;

  __shared__ float l_catt[128];
  __shared__ float wcombL[256], smsL[256], smtL[256];
  __shared__ float l_cs[128], l_ct[128], l_c[8];

  if (tid < 128) l_catt[tid] = ws[OFF_CATT + n * CC + cs * 128 + tid];
  if (tid < 64) {
    float mxFS = ws[OFF_STATS + n * 8 + 0], ZFS = ws[OFF_STATS + n * 8 + 1];
    float mxFT = ws[OFF_STATS + n * 8 + 2], ZFT = ws[OFF_STATS + n * 8 + 3];
    float mxCS = ws[OFF_STATS + n * 8 + 4], ZCS = ws[OFF_STATS + n * 8 + 5];
    float mxCT = ws[OFF_STATS + n * 8 + 6], ZCT = ws[OFF_STATS + n * 8 + 7];
    float bgc  = ws[OFF_BG + n];
    int gp = n * HWHW + pb * 256 + tid * 4;
    float4 fS0 = *(const float4*)&ws[OFF_FEA_S + gp];
    float4 fS1 = *(const float4*)&ws[OFF_FEA_S + HALF + gp];
    float4 fT0 = *(const float4*)&ws[OFF_FEA_T + gp];
    float4 fT1 = *(const float4*)&ws[OFF_FEA_T + HALF + gp];
    float4 cS0 = *(const float4*)&ws[OFF_CM_S + gp];
    float4 cS1 = *(const float4*)&ws[OFF_CM_S + HALF + gp];
    float4 cT0 = *(const float4*)&ws[OFF_CM_T + gp];
    float4 cT1 = *(const float4*)&ws[OFF_CM_T + HALF + gp];
    float4 mf = *(const float4*)&ws[OFF_MFG + gp];
    float fSa[4] = {fS0.x + fS1.x, fS0.y + fS1.y, fS0.z + fS1.z, fS0.w + fS1.w};
    float fTa[4] = {fT0.x + fT1.x, fT0.y + fT1.y, fT0.z + fT1.z, fT0.w + fT1.w};
    float cSa[4] = {cS0.x + cS1.x, cS0.y + cS1.y, cS0.z + cS1.z, cS0.w + cS1.w};
    float cTa[4] = {cT0.x + cT1.x, cT0.y + cT1.y, cT0.z + cT1.z, cT0.w + cT1.w};
    float mfa[4] = {mf.x, mf.y, mf.z, mf.w};
    float macc = 0.f;
#pragma unroll
    for (int j = 0; j < 4; j++) {
      float pT = expf(fTa[j] * (1.0f / 128.0f) - mxFT) / ZFT;
      float pS = expf(fSa[j] * (1.0f / 128.0f) - mxFS) / ZFS;
      float Satt = (float)HWHW * pT;
      float mbg = (mfa[j] > 0.f) ? 0.f : ((bgc > 0.f) ? 1.0f / bgc : 1.0f);
      wcombL[tid * 4 + j] = Satt * (C_ALPHA * mfa[j] + C_BETA * mbg);
      smsL[tid * 4 + j] = expf(cSa[j] - mxCS) / ZCS;
      smtL[tid * 4 + j] = expf(cTa[j] - mxCT) / ZCT;
      macc += fabsf(pS - pT);
    }
    macc = dpp_wave_sum(macc);
    if (tid == 63 && cs == 0) atomicAdd(&ws[OFF_SCAL + 2], macc * (float)HWHW);
  }
  __syncthreads();

  float4 sms = *(const float4*)&smsL[lane * 4];
  float4 smt = *(const float4*)&smtL[lane * 4];
  float4 wcb = *(const float4*)&wcombL[lane * 4];

  const float* baseS = S + (size_t)(n * CC + ch0) * HWHW + pix0;
  const float* baseT = T + (size_t)(n * CC + ch0) * HWHW + pix0;

  float aw[4] = {0.f, 0.f, 0.f, 0.f};

#define PROC2(c, s4, t4, ca_) { \
    float dx = s4.x - t4.x, dy = s4.y - t4.y, dz = s4.z - t4.z, dw = s4.w - t4.w; \
    aw[0] = fmaf(dx * dx, ca_, aw[0]); aw[1] = fmaf(dy * dy, ca_, aw[1]); \
    aw[2] = fmaf(dz * dz, ca_, aw[2]); aw[3] = fmaf(dw * dw, ca_, aw[3]); \
    ctxS[c] = fmaf(s4.x, sms.x, fmaf(s4.y, sms.y, fmaf(s4.z, sms.z, s4.w * sms.w))); \
    ctxT[c] = fmaf(t4.x, smt.x, fmaf(t4.y, smt.y, fmaf(t4.z, smt.z, t4.w * smt.w))); }

#pragma unroll 1
  for (int cg = 0; cg < 4; cg++) {
    const float* bS = baseS + (size_t)(cg * 4) * HWHW;
    const float* bT = baseT + (size_t)(cg * 4) * HWHW;
    float4 s0 = *(const float4*)(bS + (size_t)0 * HWHW);
    float4 s1 = *(const float4*)(bS + (size_t)1 * HWHW);
    float4 s2 = *(const float4*)(bS + (size_t)2 * HWHW);
    float4 s3 = *(const float4*)(bS + (size_t)3 * HWHW);
    float4 t0 = *(const float4*)(bT + (size_t)0 * HWHW);
    float4 t1 = *(const float4*)(bT + (size_t)1 * HWHW);
    float4 t2 = *(const float4*)(bT + (size_t)2 * HWHW);
    float4 t3 = *(const float4*)(bT + (size_t)3 * HWHW);
    float ca0 = l_catt[sl * 16 + cg * 4 + 0];
    float ca1 = l_catt[sl * 16 + cg * 4 + 1];
    float ca2 = l_catt[sl * 16 + cg * 4 + 2];
    float ca3 = l_catt[sl * 16 + cg * 4 + 3];
    float ctxS[4], ctxT[4];
    PROC2(0, s0, t0, ca0)
    PROC2(1, s1, t1, ca1)
    PROC2(2, s2, t2, ca2)
    PROC2(3, s3, t3, ca3)
#pragma unroll
    for (int c = 0; c < 4; c++) {
      float xs = dpp_wave_sum(ctxS[c]);
      float xt = dpp_wave_sum(ctxT[c]);
      if (lane == 63) {
        l_cs[sl * 16 + cg * 4 + c] = xs;
        l_ct[sl * 16 + cg * 4 + c] = xt;
      }
    }
  }
#undef PROC2

  float contrib = fmaf(aw[0], wcb.x, fmaf(aw[1], wcb.y, fmaf(aw[2], wcb.z, aw[3] * wcb.w)));
  contrib = dpp_wave_sum(contrib);
  if (lane == 63) l_c[sl] = contrib;
  __syncthreads();

  if (tid < 128) {
    int co = n * CC + cs * 128 + tid;
    atomicAdd(&ws[OFF_CTXS + co], l_cs[tid]);
    atomicAdd(&ws[OFF_CTXT + co], l_ct[tid]);
  }
  if (tid == 0) {
    float t = 0.f;
#pragma unroll
    for (int i = 0; i < 8; i++) t += l_c[i];
    atomicAdd(&ws[OFF_SCAL + 1], t);
  }
}

// ---- K5F: MLP + rela + last-block final combine. grid 8 (n) x 512.
__global__ __launch_bounds__(512) void k5F_mlp(
    const float* __restrict__ w1_s, const float* __restrict__ b1_s,
    const float* __restrict__ g_s,  const float* __restrict__ be_s,
    const float* __restrict__ w1_t, const float* __restrict__ b1_t,
    const float* __restrict__ g_t,  const float* __restrict__ be_t,
    const float* __restrict__ w2_s, const float* __restrict__ b2_s,
    const float* __restrict__ w2_t, const float* __restrict__ b2_t,
    float* __restrict__ ws, float* __restrict__ out) {
  int tid = threadIdx.x, n = blockIdx.x;
  int lane = tid & 63;
  __shared__ float ctxS[CC], ctxT[CC], ysh[128], yth[128];
  __shared__ float red[4], smr[8];

  if (tid < 256)      ctxS[tid] = ws[OFF_CTXS + n * CC + tid];
  else                ctxT[tid - 256] = ws[OFF_CTXT + n * CC + (tid - 256)];
  __syncthreads();

  int st = (tid >> 7) & 1, j = tid & 127;
  float acc = 0.f;
  if (tid < 256) {
    const float* w1 = st ? w1_t : w1_s;
    const float* b1 = st ? b1_t : b1_s;
    const float* ctx = st ? ctxT : ctxS;
    acc = b1[j];
    const float* wr = w1 + j * CC;
#pragma unroll 8
    for (int c = 0; c < CC; c += 4) {
      float4 w = *(const float4*)(wr + c);
      acc = fmaf(w.x, ctx[c], acc);
      acc = fmaf(w.y, ctx[c + 1], acc);
      acc = fmaf(w.z, ctx[c + 2], acc);
      acc = fmaf(w.w, ctx[c + 3], acc);
    }
  }

  float v = dpp_wave_sum(acc);
  if (tid < 256 && lane == 63) red[tid >> 6] = v;
  __syncthreads();
  int grp = tid >> 7;
  float mean = 0.f;
  if (tid < 256) mean = (red[grp * 2] + red[grp * 2 + 1]) * (1.0f / 128.0f);
  __syncthreads();
  float dm = acc - mean;
  v = dpp_wave_sum(dm * dm);
  if (tid < 256 && lane == 63) red[tid >> 6] = v;
  __syncthreads();
  if (tid < 256) {
    float var = (red[grp * 2] + red[grp * 2 + 1]) * (1.0f / 128.0f);
    const float* g  = st ? g_t  : g_s;
    const float* be = st ? be_t : be_s;
    float q = dm * (1.0f / sqrtf(var + C_LN_EPS)) * g[j] + be[j];
    q = q > 0.f ? q : 0.f;
    if (st == 0) ysh[j] = q;
    else         yth[j] = q;
  }
  __syncthreads();

  float rp = 0.f;
  if (tid < 256) {
    int c = tid;
    float es = b2_s[c], et = b2_t[c];
    const float* w2sr = w2_s + c * 128;
    const float* w2tr = w2_t + c * 128;
#pragma unroll 8
    for (int jj = 0; jj < 128; jj += 4) {
      float4 a = *(const float4*)(w2sr + jj);
      float4 b = *(const float4*)(w2tr + jj);
      es = fmaf(a.x, ysh[jj], es); es = fmaf(a.y, ysh[jj + 1], es);
      es = fmaf(a.z, ysh[jj + 2], es); es = fmaf(a.w, ysh[jj + 3], es);
      et = fmaf(b.x, yth[jj], et); et = fmaf(b.y, yth[jj + 1], et);
      et = fmaf(b.z, yth[jj + 2], et); et = fmaf(b.w, yth[jj + 3], et);
    }
    float e = es - et;
    rp = 2.0f * e * ws[OFF_DSUM + n * CC + c] + (float)HWHW * e * e;
  }
  rp = dpp_wave_sum(rp);
  if (lane == 63) smr[tid >> 6] = rp;
  __syncthreads();

  if (tid == 0) {
    float t = 0.f;
#pragma unroll
    for (int i = 0; i < 8; i++) t += smr[i];
    ws[OFF_RELAP + n] = t;
    __threadfence();
    int old = atomicAdd((int*)&ws[OFF_SCAL + 3], 1);
    if (old == NN - 1) {
      // last block: all RELAP writes fenced+visible; combine everything
      __threadfence();
      float relp = 0.f, mml = ws[OFF_SCAL + 2];
#pragma unroll
      for (int i = 0; i < NN; i++) {
        relp += ws[OFF_RELAP + i];
        mml  += ws[OFF_MML + i];
      }
      float rela = ws[OFF_SCAL + 0] + relp;
      out[0] = (ws[OFF_SCAL + 1] + C_GAMMA * mml + C_LAMB * rela) *
               (1.0f / (float)NN);
    }
  }
}

extern "C" void kernel_launch(void* const* d_in, const int* in_sizes, int n_in,
                              void* d_out, int out_size, void* d_ws, size_t ws_size,
                              hipStream_t stream) {
  const float* S    = (const float*)d_in[0];
  const float* T    = (const float*)d_in[1];
  const float* gt   = (const float*)d_in[2];
  const float* w_ms = (const float*)d_in[3];
  const float* w_mt = (const float*)d_in[5];
  const float* w1_s = (const float*)d_in[7];
  const float* b1_s = (const float*)d_in[8];
  const float* g_s  = (const float*)d_in[9];
  const float* be_s = (const float*)d_in[10];
  const float* w2_s = (const float*)d_in[11];
  const float* b2_s = (const float*)d_in[12];
  const float* w1_t = (const float*)d_in[13];
  const float* b1_t = (const float*)d_in[14];
  const float* g_t  = (const float*)d_in[15];
  const float* be_t = (const float*)d_in[16];
  const float* w2_t = (const float*)d_in[17];
  const float* b2_t = (const float*)d_in[18];
  float* ws = (float*)d_ws;
  float* out = (float*)d_out;

  // 5 dispatches, no memset: k0 zeroes the accumulator region itself.
  k0_maskzero<<<dim3(16, 8), dim3(256), 0, stream>>>(gt, ws);
  k1_pass1<<<dim3(64, 2, 8), dim3(512), 0, stream>>>(S, T, w_ms, w_mt, ws);
  k2C_stats<<<dim3(8), dim3(256), 0, stream>>>(ws);
  k4_pass2<<<dim3(64, 2, 8), dim3(512), 0, stream>>>(S, T, ws);
  k5F_mlp<<<dim3(8), dim3(512), 0, stream>>>(w1_s, b1_s, g_s, be_s,
                                             w1_t, b1_t, g_t, be_t,
                                             w2_s, b2_s, w2_t, b2_t, ws, out);
}

// Round 7
// 398.366 us; speedup vs baseline: 1.0753x; 1.0753x over previous
//
#include <hip/hip_runtime.h>
#include <math.h>

#define NN    8
#define CC    256
#define HWHW  16384
#define NBOX  20
#define HALF  131072   // NN*HWHW: stride between cs-halves of per-pixel arrays

constexpr float C_ALPHA = 1e-3f, C_BETA = 5e-4f, C_GAMMA = 1e-3f, C_LAMB = 5e-6f;
constexpr float C_LN_EPS = 1e-5f;

// ws layout (float offsets)
#define OFF_FEA_S   0          // [2][N][HW]
#define OFF_FEA_T   262144
#define OFF_CM_S    524288
#define OFF_CM_T    786432
#define OFF_MFG     1048576    // [N][HW]
// --- zeroed-by-k0 region: 10256 floats from OFF_CHS ---
#define OFF_CHS     1179648    // [N][C]
#define OFF_CHT     1181696
#define OFF_DSUM    1183744
#define OFF_CTXS    1185792
#define OFF_CTXT    1187840
#define OFF_BG      1189888    // [8]
#define OFF_SCAL    1189896    // [8] 0:sum(S-T)^2 1:fg/bg 2:macc 3:ticket
// --- end zero region ---
#define OFF_CATT    1189904    // [N][C]
#define OFF_STATS   1191952    // [N*8] {mxFS,ZFS,mxFT,ZFT,mxCS,ZCS,mxCT,ZCT}
#define OFF_MXP     1192016    // [4*8*16]
#define OFF_ZP      1192528
#define OFF_RELAP   1193040    // [8]
#define OFF_BGP     1193048    // [8][16]
#define OFF_MML     1193176    // [8]
#define ZERO_SPAN   10256

// ---- wave-64 reductions via DPP ----
__device__ __forceinline__ float dpp_wave_sum(float x) {
#define DPPADD(ctrl, rm) \
  x += __int_as_float(__builtin_amdgcn_update_dpp(0, __float_as_int(x), ctrl, rm, 0xf, true));
  DPPADD(0x111, 0xf)
  DPPADD(0x112, 0xf)
  DPPADD(0x114, 0xf)
  DPPADD(0x118, 0xf)
  DPPADD(0x142, 0xa)
  DPPADD(0x143, 0xc)
#undef DPPADD
  return x;  // total in lane 63
}

__device__ __forceinline__ float dpp_wave_max(float x) {
#define DPPMAX(ctrl, rm) { \
  int r_ = __builtin_amdgcn_update_dpp(__float_as_int(x), __float_as_int(x), ctrl, rm, 0xf, false); \
  x = fmaxf(x, __int_as_float(r_)); }
  DPPMAX(0x111, 0xf)
  DPPMAX(0x112, 0xf)
  DPPMAX(0x114, 0xf)
  DPPMAX(0x118, 0xf)
  DPPMAX(0x142, 0xa)
  DPPMAX(0x143, 0xc)
#undef DPPMAX
  return x;
}

__device__ __forceinline__ float block_sum256(float v, float* sm) {
  int tid = threadIdx.x;
  v = dpp_wave_sum(v);
  if ((tid & 63) == 63) sm[tid >> 6] = v;
  __syncthreads();
  float r = sm[0] + sm[1] + sm[2] + sm[3];
  __syncthreads();
  return r;
}

__device__ __forceinline__ float block_max256(float v, float* sm) {
  int tid = threadIdx.x;
  v = dpp_wave_max(v);
  if ((tid & 63) == 63) sm[tid >> 6] = v;
  __syncthreads();
  float r = fmaxf(fmaxf(sm[0], sm[1]), fmaxf(sm[2], sm[3]));
  __syncthreads();
  return r;
}

// ---- K0: mask rasterization + zero accumulators (proven R5). grid (16,8)x256
__global__ __launch_bounds__(256) void k0_maskzero(const float* __restrict__ gt,
                                                   float* __restrict__ ws) {
  int tid = threadIdx.x;
  int pbB = blockIdx.x, n = blockIdx.y;
  int pix0 = pbB * 1024 + tid * 4;
  int gi = (n * 16 + pbB) * 256 + tid;
  if (gi < ZERO_SPAN) ws[OFF_CHS + gi] = 0.f;

  __shared__ float bx[NBOX][5];
  __shared__ float l_bg[4];
  if (tid < NBOX) {
    const float* g = gt + (n * NBOX + tid) * 4;
    float wmin = floorf(g[0] * 0.125f);
    float hmin = floorf(g[1] * 0.125f);
    float wmax = ceilf(g[2] * 0.125f);
    float hmax = ceilf(g[3] * 0.125f);
    bx[tid][0] = wmin; bx[tid][1] = hmin; bx[tid][2] = wmax; bx[tid][3] = hmax;
    bx[tid][4] = 1.0f / ((hmax + 1.0f - hmin) * (wmax + 1.0f - wmin));
  }
  __syncthreads();
  float best[4] = {0.f, 0.f, 0.f, 0.f};
#pragma unroll
  for (int b = 0; b < NBOX; b++) {
    float wmin = bx[b][0], hmin = bx[b][1], wmax = bx[b][2], hmax = bx[b][3];
    float ar = bx[b][4];
#pragma unroll
    for (int j = 0; j < 4; j++) {
      int pix = pix0 + j;
      float hf = (float)(pix >> 7), wf = (float)(pix & 127);
      bool in = (hf >= hmin) && (hf <= hmax) && (wf >= wmin) && (wf <= wmax);
      best[j] = in ? fmaxf(best[j], ar) : best[j];
    }
  }
  float4 bo;
  bo.x = best[0]; bo.y = best[1]; bo.z = best[2]; bo.w = best[3];
  *(float4*)&ws[OFF_MFG + n * HWHW + pix0] = bo;
  float bg = (best[0] > 0.f ? 0.f : 1.f) + (best[1] > 0.f ? 0.f : 1.f) +
             (best[2] > 0.f ? 0.f : 1.f) + (best[3] > 0.f ? 0.f : 1.f);
  bg = dpp_wave_sum(bg);
  if ((tid & 63) == 63) l_bg[tid >> 6] = bg;
  __syncthreads();
  if (tid == 0)
    ws[OFF_BGP + n * 16 + pbB] = l_bg[0] + l_bg[1] + l_bg[2] + l_bg[3];
}

// ---- K1: pass 1 (measured-best R2 body). grid (64,2,8) x 512
__global__ __launch_bounds__(512, 2) void k1_pass1(
    const float* __restrict__ S, const float* __restrict__ T,
    const float* __restrict__ w_ms, const float* __restrict__ w_mt,
    float* __restrict__ ws) {
  int tid = threadIdx.x;
  int lane = tid & 63, sl = tid >> 6;
  int pb = blockIdx.x, cs = blockIdx.y, n = blockIdx.z;
  int pix0 = pb * 256 + lane * 4;
  int ch0 = cs * 128 + sl * 16;

  __shared__ float l_wS[128], l_wT[128];
  __shared__ float f_feaS[256], f_feaT[256], f_cmS[256], f_cmT[256];
  __shared__ float l_chS[128], l_chT[128], l_D[128];
  __shared__ float l_sq[8];

  if (tid < 128) {
    l_wS[tid] = w_ms[cs * 128 + tid];
    l_wT[tid] = w_mt[cs * 128 + tid];
  }
  if (tid < 256) {
    f_feaS[tid] = 0.f; f_feaT[tid] = 0.f; f_cmS[tid] = 0.f; f_cmT[tid] = 0.f;
  }
  __syncthreads();

  const float* baseS = S + (size_t)(n * CC + ch0) * HWHW + pix0;
  const float* baseT = T + (size_t)(n * CC + ch0) * HWHW + pix0;

  float fS[4] = {0.f, 0.f, 0.f, 0.f}, fT[4] = {0.f, 0.f, 0.f, 0.f};
  float cS[4] = {0.f, 0.f, 0.f, 0.f}, cT[4] = {0.f, 0.f, 0.f, 0.f};
  float sq = 0.f;

#define PROC1(c, s4, t4, wS_, wT_) { \
    float asx = fabsf(s4.x), asy = fabsf(s4.y), asz = fabsf(s4.z), asw = fabsf(s4.w); \
    float atx = fabsf(t4.x), aty = fabsf(t4.y), atz = fabsf(t4.z), atw = fabsf(t4.w); \
    fS[0] += asx; fS[1] += asy; fS[2] += asz; fS[3] += asw; \
    fT[0] += atx; fT[1] += aty; fT[2] += atz; fT[3] += atw; \
    chS[c] = (asx + asy) + (asz + asw); \
    chT[c] = (atx + aty) + (atz + atw); \
    cS[0] = fmaf(s4.x, wS_, cS[0]); cS[1] = fmaf(s4.y, wS_, cS[1]); \
    cS[2] = fmaf(s4.z, wS_, cS[2]); cS[3] = fmaf(s4.w, wS_, cS[3]); \
    cT[0] = fmaf(t4.x, wT_, cT[0]); cT[1] = fmaf(t4.y, wT_, cT[1]); \
    cT[2] = fmaf(t4.z, wT_, cT[2]); cT[3] = fmaf(t4.w, wT_, cT[3]); \
    float dx = s4.x - t4.x, dy = s4.y - t4.y, dz = s4.z - t4.z, dw = s4.w - t4.w; \
    sq = fmaf(dx, dx, sq); sq = fmaf(dy, dy, sq); \
    sq = fmaf(dz, dz, sq); sq = fmaf(dw, dw, sq); \
    D[c] = (dx + dy) + (dz + dw); }

#pragma unroll 1
  for (int cg4 = 0; cg4 < 4; cg4++) {
    const float* bS = baseS + (size_t)(cg4 * 4) * HWHW;
    const float* bT = baseT + (size_t)(cg4 * 4) * HWHW;
    float4 s0 = *(const float4*)(bS + (size_t)0 * HWHW);
    float4 s1 = *(const float4*)(bS + (size_t)1 * HWHW);
    float4 s2 = *(const float4*)(bS + (size_t)2 * HWHW);
    float4 s3 = *(const float4*)(bS + (size_t)3 * HWHW);
    float4 t0 = *(const float4*)(bT + (size_t)0 * HWHW);
    float4 t1 = *(const float4*)(bT + (size_t)1 * HWHW);
    float4 t2 = *(const float4*)(bT + (size_t)2 * HWHW);
    float4 t3 = *(const float4*)(bT + (size_t)3 * HWHW);
    float wS0 = l_wS[sl * 16 + cg4 * 4 + 0], wT0 = l_wT[sl * 16 + cg4 * 4 + 0];
    float wS1 = l_wS[sl * 16 + cg4 * 4 + 1], wT1 = l_wT[sl * 16 + cg4 * 4 + 1];
    float wS2 = l_wS[sl * 16 + cg4 * 4 + 2], wT2 = l_wT[sl * 16 + cg4 * 4 + 2];
    float wS3 = l_wS[sl * 16 + cg4 * 4 + 3], wT3 = l_wT[sl * 16 + cg4 * 4 + 3];
    float chS[4], chT[4], D[4];
    PROC1(0, s0, t0, wS0, wT0)
    PROC1(1, s1, t1, wS1, wT1)
    PROC1(2, s2, t2, wS2, wT2)
    PROC1(3, s3, t3, wS3, wT3)
#pragma unroll
    for (int c = 0; c < 4; c++) {
      float a = dpp_wave_sum(chS[c]);
      float b = dpp_wave_sum(chT[c]);
      float d = dpp_wave_sum(D[c]);
      if (lane == 63) {
        l_chS[sl * 16 + cg4 * 4 + c] = a;
        l_chT[sl * 16 + cg4 * 4 + c] = b;
        l_D[sl * 16 + cg4 * 4 + c]   = d;
      }
    }
  }
#undef PROC1

  atomicAdd(&f_feaS[lane * 4 + 0], fS[0]); atomicAdd(&f_feaS[lane * 4 + 1], fS[1]);
  atomicAdd(&f_feaS[lane * 4 + 2], fS[2]); atomicAdd(&f_feaS[lane * 4 + 3], fS[3]);
  atomicAdd(&f_feaT[lane * 4 + 0], fT[0]); atomicAdd(&f_feaT[lane * 4 + 1], fT[1]);
  atomicAdd(&f_feaT[lane * 4 + 2], fT[2]); atomicAdd(&f_feaT[lane * 4 + 3], fT[3]);
  atomicAdd(&f_cmS[lane * 4 + 0], cS[0]); atomicAdd(&f_cmS[lane * 4 + 1], cS[1]);
  atomicAdd(&f_cmS[lane * 4 + 2], cS[2]); atomicAdd(&f_cmS[lane * 4 + 3], cS[3]);
  atomicAdd(&f_cmT[lane * 4 + 0], cT[0]); atomicAdd(&f_cmT[lane * 4 + 1], cT[1]);
  atomicAdd(&f_cmT[lane * 4 + 2], cT[2]); atomicAdd(&f_cmT[lane * 4 + 3], cT[3]);

  sq = dpp_wave_sum(sq);
  if (lane == 63) l_sq[sl] = sq;
  __syncthreads();

  if (tid < 256) {
    int gp = cs * HALF + n * HWHW + pb * 256 + tid;
    ws[OFF_FEA_S + gp] = f_feaS[tid];
    ws[OFF_FEA_T + gp] = f_feaT[tid];
    ws[OFF_CM_S + gp]  = f_cmS[tid];
    ws[OFF_CM_T + gp]  = f_cmT[tid];
  }
  if (tid < 128) {
    int co = n * CC + cs * 128 + tid;
    atomicAdd(&ws[OFF_CHS + co],  l_chS[tid]);
    atomicAdd(&ws[OFF_CHT + co],  l_chT[tid]);
    atomicAdd(&ws[OFF_DSUM + co], l_D[tid]);
  }
  if (tid == 0) {
    float t = 0.f;
#pragma unroll
    for (int i = 0; i < 8; i++) t += l_sq[i];
    atomicAdd(&ws[OFF_SCAL + 0], t);
  }
}

// ---- K2B: WIDE per-tile softmax stats (proven R4 phase B). grid (16,8) x 256
__global__ __launch_bounds__(256) void k2B_stats(float* __restrict__ ws) {
  int tid = threadIdx.x;
  int pbB = blockIdx.x, n = blockIdx.y;
  int pix0 = pbB * 1024 + tid * 4;
  __shared__ float sm[4];

  int gp = n * HWHW + pix0;
  const int   offs[4]   = {OFF_FEA_S, OFF_FEA_T, OFF_CM_S, OFF_CM_T};
  const float scales[4] = {1.0f / 128.0f, 1.0f / 128.0f, 1.0f, 1.0f};
#pragma unroll
  for (int a = 0; a < 4; a++) {
    float4 v0 = *(const float4*)&ws[offs[a] + gp];
    float4 v1 = *(const float4*)&ws[offs[a] + HALF + gp];
    float sc = scales[a];
    float vx = (v0.x + v1.x) * sc, vy = (v0.y + v1.y) * sc;
    float vz = (v0.z + v1.z) * sc, vw = (v0.w + v1.w) * sc;
    float mx = fmaxf(fmaxf(vx, vy), fmaxf(vz, vw));
    mx = block_max256(mx, sm);
    float z = expf(vx - mx) + expf(vy - mx) + expf(vz - mx) + expf(vw - mx);
    z = block_sum256(z, sm);
    if (tid == 0) {
      ws[OFF_MXP + a * 128 + n * 16 + pbB] = mx;
      ws[OFF_ZP + a * 128 + n * 16 + pbB]  = z;
    }
  }
}

// ---- KC: BG sum + stats combine + channel softmax (thin). grid 8 x 256
__global__ __launch_bounds__(256) void kC_stats2(float* __restrict__ ws) {
  int tid = threadIdx.x, n = blockIdx.x;
  __shared__ float sm[4];

  if (tid == 0) {
    float b = 0.f;
    for (int i = 0; i < 16; i++) b += ws[OFF_BGP + n * 16 + i];
    ws[OFF_BG + n] = b;
  }
  if (tid < 4) {
    int a = tid;
    float m = -1e30f;
    for (int i = 0; i < 16; i++)
      m = fmaxf(m, ws[OFF_MXP + a * 128 + n * 16 + i]);
    float Z = 0.f;
    for (int i = 0; i < 16; i++)
      Z += ws[OFF_ZP + a * 128 + n * 16 + i] *
           expf(ws[OFF_MXP + a * 128 + n * 16 + i] - m);
    ws[OFF_STATS + n * 8 + 2 * a]     = m;
    ws[OFF_STATS + n * 8 + 2 * a + 1] = Z;
  }

  float chS = ws[OFF_CHS + n * CC + tid];
  float chT = ws[OFF_CHT + n * CC + tid];
  float lS = chS * (1.0f / 8192.0f), lT = chT * (1.0f / 8192.0f);
  float mS = block_max256(lS, sm);
  float mT = block_max256(lT, sm);
  float eS = expf(lS - mS), eT = expf(lT - mT);
  float ZS = block_sum256(eS, sm);
  float ZT = block_sum256(eT, sm);
  float cattS = (float)CC * eS / ZS;
  float cattT = (float)CC * eT / ZT;
  ws[OFF_CATT + n * CC + tid] = cattT;
  float mml = block_sum256(fabsf(cattS - cattT), sm);
  if (tid == 0) ws[OFF_MML + n] = mml;
}

// ---- K4: pass 2 (proven body). grid (64,2,8) x 512
__global__ __launch_bounds__(512, 2) void k4_pass2(
    const float* __restrict__ S, const float* __restrict__ T,
    float* __restrict__ ws) {
  int tid = threadIdx.x;
  int lane = tid & 63, sl = tid >> 6;
  int pb = blockIdx.x, cs = blockIdx.y, n = blockIdx.z;
  int pix0 = pb * 256 + lane * 4;
  int ch0 = cs * 128 + sl * 16;

  __shared__ float l_catt[128];
  __shared__ float wcombL[256], smsL[256], smtL[256];
  __shared__ float l_cs[128], l_ct[128], l_c[8];

  if (tid < 128) l_catt[tid] = ws[OFF_CATT + n * CC + cs * 128 + tid];
  if (tid < 64) {
    float mxFS = ws[OFF_STATS + n * 8 + 0], ZFS = ws[OFF_STATS + n * 8 + 1];
    float mxFT = ws[OFF_STATS + n * 8 + 2], ZFT = ws[OFF_STATS + n * 8 + 3];
    float mxCS = ws[OFF_STATS + n * 8 + 4], ZCS = ws[OFF_STATS + n * 8 + 5];
    float mxCT = ws[OFF_STATS + n * 8 + 6], ZCT = ws[OFF_STATS + n * 8 + 7];
    float bgc  = ws[OFF_BG + n];
    int gp = n * HWHW + pb * 256 + tid * 4;
    float4 fS0 = *(const float4*)&ws[OFF_FEA_S + gp];
    float4 fS1 = *(const float4*)&ws[OFF_FEA_S + HALF + gp];
    float4 fT0 = *(const float4*)&ws[OFF_FEA_T + gp];
    float4 fT1 = *(const float4*)&ws[OFF_FEA_T + HALF + gp];
    float4 cS0 = *(const float4*)&ws[OFF_CM_S + gp];
    float4 cS1 = *(const float4*)&ws[OFF_CM_S + HALF + gp];
    float4 cT0 = *(const float4*)&ws[OFF_CM_T + gp];
    float4 cT1 = *(const float4*)&ws[OFF_CM_T + HALF + gp];
    float4 mf = *(const float4*)&ws[OFF_MFG + gp];
    float fSa[4] = {fS0.x + fS1.x, fS0.y + fS1.y, fS0.z + fS1.z, fS0.w + fS1.w};
    float fTa[4] = {fT0.x + fT1.x, fT0.y + fT1.y, fT0.z + fT1.z, fT0.w + fT1.w};
    float cSa[4] = {cS0.x + cS1.x, cS0.y + cS1.y, cS0.z + cS1.z, cS0.w + cS1.w};
    float cTa[4] = {cT0.x + cT1.x, cT0.y + cT1.y, cT0.z + cT1.z, cT0.w + cT1.w};
    float mfa[4] = {mf.x, mf.y, mf.z, mf.w};
    float macc = 0.f;
#pragma unroll
    for (int j = 0; j < 4; j++) {
      float pT = expf(fTa[j] * (1.0f / 128.0f) - mxFT) / ZFT;
      float pS = expf(fSa[j] * (1.0f / 128.0f) - mxFS) / ZFS;
      float Satt = (float)HWHW * pT;
      float mbg = (mfa[j] > 0.f) ? 0.f : ((bgc > 0.f) ? 1.0f / bgc : 1.0f);
      wcombL[tid * 4 + j] = Satt * (C_ALPHA * mfa[j] + C_BETA * mbg);
      smsL[tid * 4 + j] = expf(cSa[j] - mxCS) / ZCS;
      smtL[tid * 4 + j] = expf(cTa[j] - mxCT) / ZCT;
      macc += fabsf(pS - pT);
    }
    macc = dpp_wave_sum(macc);
    if (tid == 63 && cs == 0) atomicAdd(&ws[OFF_SCAL + 2], macc * (float)HWHW);
  }
  __syncthreads();

  float4 sms = *(const float4*)&smsL[lane * 4];
  float4 smt = *(const float4*)&smtL[lane * 4];
  float4 wcb = *(const float4*)&wcombL[lane * 4];

  const float* baseS = S + (size_t)(n * CC + ch0) * HWHW + pix0;
  const float* baseT = T + (size_t)(n * CC + ch0) * HWHW + pix0;

  float aw[4] = {0.f, 0.f, 0.f, 0.f};

#define PROC2(c, s4, t4, ca_) { \
    float dx = s4.x - t4.x, dy = s4.y - t4.y, dz = s4.z - t4.z, dw = s4.w - t4.w; \
    aw[0] = fmaf(dx * dx, ca_, aw[0]); aw[1] = fmaf(dy * dy, ca_, aw[1]); \
    aw[2] = fmaf(dz * dz, ca_, aw[2]); aw[3] = fmaf(dw * dw, ca_, aw[3]); \
    ctxS[c] = fmaf(s4.x, sms.x, fmaf(s4.y, sms.y, fmaf(s4.z, sms.z, s4.w * sms.w))); \
    ctxT[c] = fmaf(t4.x, smt.x, fmaf(t4.y, smt.y, fmaf(t4.z, smt.z, t4.w * smt.w))); }

#pragma unroll 1
  for (int cg4 = 0; cg4 < 4; cg4++) {
    const float* bS = baseS + (size_t)(cg4 * 4) * HWHW;
    const float* bT = baseT + (size_t)(cg4 * 4) * HWHW;
    float4 s0 = *(const float4*)(bS + (size_t)0 * HWHW);
    float4 s1 = *(const float4*)(bS + (size_t)1 * HWHW);
    float4 s2 = *(const float4*)(bS + (size_t)2 * HWHW);
    float4 s3 = *(const float4*)(bS + (size_t)3 * HWHW);
    float4 t0 = *(const float4*)(bT + (size_t)0 * HWHW);
    float4 t1 = *(const float4*)(bT + (size_t)1 * HWHW);
    float4 t2 = *(const float4*)(bT + (size_t)2 * HWHW);
    float4 t3 = *(const float4*)(bT + (size_t)3 * HWHW);
    float ca0 = l_catt[sl * 16 + cg4 * 4 + 0];
    float ca1 = l_catt[sl * 16 + cg4 * 4 + 1];
    float ca2 = l_catt[sl * 16 + cg4 * 4 + 2];
    float ca3 = l_catt[sl * 16 + cg4 * 4 + 3];
    float ctxS[4], ctxT[4];
    PROC2(0, s0, t0, ca0)
    PROC2(1, s1, t1, ca1)
    PROC2(2, s2, t2, ca2)
    PROC2(3, s3, t3, ca3)
#pragma unroll
    for (int c = 0; c < 4; c++) {
      float xs = dpp_wave_sum(ctxS[c]);
      float xt = dpp_wave_sum(ctxT[c]);
      if (lane == 63) {
        l_cs[sl * 16 + cg4 * 4 + c] = xs;
        l_ct[sl * 16 + cg4 * 4 + c] = xt;
      }
    }
  }
#undef PROC2

  float contrib = fmaf(aw[0], wcb.x, fmaf(aw[1], wcb.y, fmaf(aw[2], wcb.z, aw[3] * wcb.w)));
  contrib = dpp_wave_sum(contrib);
  if (lane == 63) l_c[sl] = contrib;
  __syncthreads();

  if (tid < 128) {
    int co = n * CC + cs * 128 + tid;
    atomicAdd(&ws[OFF_CTXS + co], l_cs[tid]);
    atomicAdd(&ws[OFF_CTXT + co], l_ct[tid]);
  }
  if (tid == 0) {
    float t = 0.f;
#pragma unroll
    for (int i = 0; i < 8; i++) t += l_c[i];
    atomicAdd(&ws[OFF_SCAL + 1], t);
  }
}

// ---- K5F: MLP + rela + ticket final combine (proven R5). grid 8 x 512
__global__ __launch_bounds__(512) void k5F_mlp(
    const float* __restrict__ w1_s, const float* __restrict__ b1_s,
    const float* __restrict__ g_s,  const float* __restrict__ be_s,
    const float* __restrict__ w1_t, const float* __restrict__ b1_t,
    const float* __restrict__ g_t,  const float* __restrict__ be_t,
    const float* __restrict__ w2_s, const float* __restrict__ b2_s,
    const float* __restrict__ w2_t, const float* __restrict__ b2_t,
    float* __restrict__ ws, float* __restrict__ out) {
  int tid = threadIdx.x, n = blockIdx.x;
  int lane = tid & 63;
  __shared__ float ctxS[CC], ctxT[CC], ysh[128], yth[128];
  __shared__ float red[4], smr[8];

  if (tid < 256)      ctxS[tid] = ws[OFF_CTXS + n * CC + tid];
  else                ctxT[tid - 256] = ws[OFF_CTXT + n * CC + (tid - 256)];
  __syncthreads();

  int st = (tid >> 7) & 1, j = tid & 127;
  float acc = 0.f;
  if (tid < 256) {
    const float* w1 = st ? w1_t : w1_s;
    const float* b1 = st ? b1_t : b1_s;
    const float* ctx = st ? ctxT : ctxS;
    acc = b1[j];
    const float* wr = w1 + j * CC;
#pragma unroll 8
    for (int c = 0; c < CC; c += 4) {
      float4 w = *(const float4*)(wr + c);
      acc = fmaf(w.x, ctx[c], acc);
      acc = fmaf(w.y, ctx[c + 1], acc);
      acc = fmaf(w.z, ctx[c + 2], acc);
      acc = fmaf(w.w, ctx[c + 3], acc);
    }
  }

  float v = dpp_wave_sum(acc);
  if (tid < 256 && lane == 63) red[tid >> 6] = v;
  __syncthreads();
  int grp = tid >> 7;
  float mean = 0.f;
  if (tid < 256) mean = (red[grp * 2] + red[grp * 2 + 1]) * (1.0f / 128.0f);
  __syncthreads();
  float dm = acc - mean;
  v = dpp_wave_sum(dm * dm);
  if (tid < 256 && lane == 63) red[tid >> 6] = v;
  __syncthreads();
  if (tid < 256) {
    float var = (red[grp * 2] + red[grp * 2 + 1]) * (1.0f / 128.0f);
    const float* g  = st ? g_t  : g_s;
    const float* be = st ? be_t : be_s;
    float q = dm * (1.0f / sqrtf(var + C_LN_EPS)) * g[j] + be[j];
    q = q > 0.f ? q : 0.f;
    if (st == 0) ysh[j] = q;
    else         yth[j] = q;
  }
  __syncthreads();

  float rp = 0.f;
  if (tid < 256) {
    int c = tid;
    float es = b2_s[c], et = b2_t[c];
    const float* w2sr = w2_s + c * 128;
    const float* w2tr = w2_t + c * 128;
#pragma unroll 8
    for (int jj = 0; jj < 128; jj += 4) {
      float4 a = *(const float4*)(w2sr + jj);
      float4 b = *(const float4*)(w2tr + jj);
      es = fmaf(a.x, ysh[jj], es); es = fmaf(a.y, ysh[jj + 1], es);
      es = fmaf(a.z, ysh[jj + 2], es); es = fmaf(a.w, ysh[jj + 3], es);
      et = fmaf(b.x, yth[jj], et); et = fmaf(b.y, yth[jj + 1], et);
      et = fmaf(b.z, yth[jj + 2], et); et = fmaf(b.w, yth[jj + 3], et);
    }
    float e = es - et;
    rp = 2.0f * e * ws[OFF_DSUM + n * CC + c] + (float)HWHW * e * e;
  }
  rp = dpp_wave_sum(rp);
  if (lane == 63) smr[tid >> 6] = rp;
  __syncthreads();

  if (tid == 0) {
    float t = 0.f;
#pragma unroll
    for (int i = 0; i < 8; i++) t += smr[i];
    ws[OFF_RELAP + n] = t;
    __threadfence();
    int old = atomicAdd((int*)&ws[OFF_SCAL + 3], 1);
    if (old == NN - 1) {
      __threadfence();
      float relp = 0.f, mml = ws[OFF_SCAL + 2];
#pragma unroll
      for (int i = 0; i < NN; i++) {
        relp += ws[OFF_RELAP + i];
        mml  += ws[OFF_MML + i];
      }
      float rela = ws[OFF_SCAL + 0] + relp;
      out[0] = (ws[OFF_SCAL + 1] + C_GAMMA * mml + C_LAMB * rela) *
               (1.0f / (float)NN);
    }
  }
}

extern "C" void kernel_launch(void* const* d_in, const int* in_sizes, int n_in,
                              void* d_out, int out_size, void* d_ws, size_t ws_size,
                              hipStream_t stream) {
  const float* S    = (const float*)d_in[0];
  const float* T    = (const float*)d_in[1];
  const float* gt   = (const float*)d_in[2];
  const float* w_ms = (const float*)d_in[3];
  const float* w_mt = (const float*)d_in[5];
  const float* w1_s = (const float*)d_in[7];
  const float* b1_s = (const float*)d_in[8];
  const float* g_s  = (const float*)d_in[9];
  const float* be_s = (const float*)d_in[10];
  const float* w2_s = (const float*)d_in[11];
  const float* b2_s = (const float*)d_in[12];
  const float* w1_t = (const float*)d_in[13];
  const float* b1_t = (const float*)d_in[14];
  const float* g_t  = (const float*)d_in[15];
  const float* be_t = (const float*)d_in[16];
  const float* w2_t = (const float*)d_in[17];
  const float* b2_t = (const float*)d_in[18];
  float* ws = (float*)d_ws;
  float* out = (float*)d_out;

  // 6 graph nodes, all components individually harness-proven.
  k0_maskzero<<<dim3(16, 8), dim3(256), 0, stream>>>(gt, ws);
  k1_pass1<<<dim3(64, 2, 8), dim3(512), 0, stream>>>(S, T, w_ms, w_mt, ws);
  k2B_stats<<<dim3(16, 8), dim3(256), 0, stream>>>(ws);
  kC_stats2<<<dim3(8), dim3(256), 0, stream>>>(ws);
  k4_pass2<<<dim3(64, 2, 8), dim3(512), 0, stream>>>(S, T, ws);
  k5F_mlp<<<dim3(8), dim3(512), 0, stream>>>(w1_s, b1_s, g_s, be_s,
                                             w1_t, b1_t, g_t, be_t,
                                             w2_s, b2_s, w2_t, b2_t, ws, out);
}